// Round 1
// 1048.193 us; speedup vs baseline: 1.0180x; 1.0180x over previous
//
#include <hip/hip_runtime.h>
#include <stdint.h>
#include <math.h>

// Problem constants
#define D_MODEL 768
#define NTOK    4096      // B*S = 2*2048
#define SEQ     2048
#define NHEAD   12
#define HDIM    64
#define D_FF    3072
#define QKV_N   2304      // 3*D_MODEL

typedef unsigned short ushort_t;  // raw bf16 bits
typedef short  sh4    __attribute__((ext_vector_type(4)));   // NOT short4: HIP defines that
typedef short  short8 __attribute__((ext_vector_type(8)));
typedef float  f32x4  __attribute__((ext_vector_type(4)));
typedef float  f32x16 __attribute__((ext_vector_type(16)));

__device__ __forceinline__ float b2f(ushort_t u) {
  union { unsigned int u; float f; } v; v.u = ((unsigned int)u) << 16; return v.f;
}
__device__ __forceinline__ ushort_t f2b(float f) {
  union { float f; unsigned int u; } v; v.f = f;
  unsigned int u = v.u;
  return (ushort_t)((u + 0x7fffu + ((u >> 16) & 1u)) >> 16);  // RNE
}
__device__ __forceinline__ unsigned cvtpk_bf16(float lo, float hi) {
  unsigned r;
  asm("v_cvt_pk_bf16_f32 %0, %1, %2" : "=v"(r) : "v"(lo), "v"(hi));
  return r;
}

// ---------------------------------------------------------------- layer transpose+cast
// All 4 weight matrices of one layer, [K,N] fp32 -> [N,K] bf16, one launch.
__global__ __launch_bounds__(256) void transpose_layer(
    const float* __restrict__ qkv_w, const float* __restrict__ out_w,
    const float* __restrict__ fc1_w, const float* __restrict__ fc2_w,
    ushort_t* __restrict__ qkvT, ushort_t* __restrict__ outT,
    ushort_t* __restrict__ f1T, ushort_t* __restrict__ f2T) {
  __shared__ ushort_t tile[32][33];
  int bid = blockIdx.x;
  const float* src; ushort_t* dst; int K, N, tn, tk;
  if (bid < 1728)      { src = qkv_w; dst = qkvT; K = 768;  N = 2304; tn = bid % 72;  tk = bid / 72; }
  else if (bid < 2304) { int b = bid - 1728; src = out_w; dst = outT; K = 768;  N = 768;  tn = b % 24; tk = b / 24; }
  else if (bid < 4608) { int b = bid - 2304; src = fc1_w; dst = f1T;  K = 768;  N = 3072; tn = b % 96; tk = b / 96; }
  else                 { int b = bid - 4608; src = fc2_w; dst = f2T;  K = 3072; N = 768;  tn = b % 24; tk = b / 24; }
  int n0 = tn * 32, k0 = tk * 32;
  int tx = threadIdx.x, ty = threadIdx.y;       // (32,8)
  #pragma unroll
  for (int i = 0; i < 32; i += 8)
    tile[ty + i][tx] = f2b(src[(size_t)(k0 + ty + i) * N + n0 + tx]);
  __syncthreads();
  #pragma unroll
  for (int i = 0; i < 32; i += 8)
    dst[(size_t)(n0 + ty + i) * K + k0 + tx] = tile[tx][ty + i];
}

// ---------------------------------------------------------------- layernorm
__global__ __launch_bounds__(256) void ln_kernel(const float* __restrict__ x,
                                                 const float* __restrict__ w,
                                                 const float* __restrict__ b,
                                                 ushort_t* __restrict__ out) {
  __shared__ float red[4];
  int tok = blockIdx.x, t = threadIdx.x;
  const float* xr = x + (size_t)tok * D_MODEL;
  float v0 = xr[t], v1 = xr[t + 256], v2 = xr[t + 512];
  float s = v0 + v1 + v2;
  #pragma unroll
  for (int o = 1; o < 64; o <<= 1) s += __shfl_xor(s, o, 64);
  if ((t & 63) == 0) red[t >> 6] = s;
  __syncthreads();
  float mean = (red[0] + red[1] + red[2] + red[3]) * (1.0f / 768.0f);
  __syncthreads();
  float d0 = v0 - mean, d1 = v1 - mean, d2 = v2 - mean;
  float q = d0 * d0 + d1 * d1 + d2 * d2;
  #pragma unroll
  for (int o = 1; o < 64; o <<= 1) q += __shfl_xor(q, o, 64);
  if ((t & 63) == 0) red[t >> 6] = q;
  __syncthreads();
  float var = (red[0] + red[1] + red[2] + red[3]) * (1.0f / 768.0f);
  float rs = rsqrtf(var + 1e-5f);
  ushort_t* orow = out + (size_t)tok * D_MODEL;
  orow[t]       = f2b(d0 * rs * w[t]       + b[t]);
  orow[t + 256] = f2b(d1 * rs * w[t + 256] + b[t + 256]);
  orow[t + 512] = f2b(d2 * rs * w[t + 512] + b[t + 512]);
}

// ---------------------------------------------------------------- GEMM (MFMA bf16)
// C[M,N] = A[M,K] * BT[N,K]^T + bias, 128 x TN tile, BK=32, 256 threads.
// DOUBLE-BUFFERED K-loop: one barrier/iter; prefetch of tile k+1 issued right
// after the barrier -> it gets the whole MFMA phase to fly before the next
// barrier's vmcnt drain (vs ~0 cycles in the 2-barrier structure).
// EPI: 0 bias->bf16 | 1 bias+gelu->bf16 | 2 bias+resid->fp32
template <int EPI, int TN>
__global__ __launch_bounds__(256) void gemm_kernel(
    const ushort_t* __restrict__ A, const ushort_t* __restrict__ BT,
    const float* __restrict__ bias, const float* __restrict__ resid,
    float* __restrict__ Cf, ushort_t* __restrict__ Cb, int M, int N, int K) {
  constexpr int NI = (TN == 128) ? 4 : 2;
  __shared__ ushort_t As[2][128 * 32];
  __shared__ ushort_t Bs[2][TN * 32];
  int t = threadIdx.x;
  int lane = t & 63, wave = t >> 6;
  int m0 = blockIdx.y * 128, n0 = blockIdx.x * TN;
  int wm = (TN == 128) ? (wave & 1) * 64 : wave * 32;
  int wn = (TN == 128) ? (wave >> 1) * 64 : 0;
  int quad = lane >> 4, l16 = lane & 15;
  int kq = quad * 8;
  int lrow = lane >> 2, lcol = (lane & 3) * 8;   // staging: 16B per lane

  auto stage = [&](int k0, int buf) {
    #pragma unroll
    for (int c = 0; c < 2; ++c) {
      int rowA = wave * 32 + c * 16 + lrow;
      const ushort_t* ga = A + (size_t)(m0 + rowA) * K + k0 + lcol;
      ushort_t* la = &As[buf][(wave * 32 + c * 16) * 32];
      __builtin_amdgcn_global_load_lds((const __attribute__((address_space(1))) void*)ga,
                                       (__attribute__((address_space(3))) void*)la, 16, 0, 0);
      if (TN == 128 || c == 0) {
        int rowB = (TN == 128) ? rowA : (wave * 16 + lrow);
        const ushort_t* gb = BT + (size_t)(n0 + rowB) * K + k0 + lcol;
        ushort_t* lb = (TN == 128) ? &Bs[buf][(wave * 32 + c * 16) * 32]
                                   : &Bs[buf][(wave * 16) * 32];
        __builtin_amdgcn_global_load_lds((const __attribute__((address_space(1))) void*)gb,
                                         (__attribute__((address_space(3))) void*)lb, 16, 0, 0);
      }
    }
  };

  f32x4 acc[NI][4];
  #pragma unroll
  for (int i = 0; i < NI; ++i)
    #pragma unroll
    for (int j = 0; j < 4; ++j) acc[i][j] = (f32x4){0.f, 0.f, 0.f, 0.f};

  stage(0, 0);                      // prologue prefetch
  int nk = K / 32;
  for (int ki = 0; ki < nk; ++ki) {
    int cur = ki & 1;
    __syncthreads();                // tile ki resident; prev reads of buf[cur^1] done
    if (ki + 1 < nk) stage((ki + 1) * 32, cur ^ 1);
    short8 af[NI], bf[4];
    #pragma unroll
    for (int i = 0; i < NI; ++i)
      af[i] = *(const short8*)&As[cur][(wm + i * 16 + l16) * 32 + kq];
    #pragma unroll
    for (int j = 0; j < 4; ++j)
      bf[j] = *(const short8*)&Bs[cur][(wn + j * 16 + l16) * 32 + kq];
    #pragma unroll
    for (int i = 0; i < NI; ++i)
      #pragma unroll
      for (int j = 0; j < 4; ++j)
        acc[i][j] = __builtin_amdgcn_mfma_f32_16x16x32_bf16(af[i], bf[j], acc[i][j], 0, 0, 0);
  }

  #pragma unroll
  for (int i = 0; i < NI; ++i) {
    #pragma unroll
    for (int j = 0; j < 4; ++j) {
      int col = n0 + wn + j * 16 + l16;
      float bv = bias[col];
      #pragma unroll
      for (int r = 0; r < 4; ++r) {
        int row = m0 + wm + i * 16 + quad * 4 + r;
        float v = acc[i][j][r] + bv;
        if (EPI == 1) v = 0.5f * v * (1.0f + erff(v * 0.70710678118654752f));
        if (EPI == 2) v += resid[(size_t)row * N + col];
        if (EPI == 2) Cf[(size_t)row * N + col] = v;
        else          Cb[(size_t)row * N + col] = f2b(v);
      }
    }
  }
}

// ---------------------------------------------------------------- attention (MFMA 32x32, in-register softmax)
// qkv bf16 [NTOK, 2304]; token t, head hd: [hd*192 + (q:0|k:64|v:128) + d]
// Block: 128 q-rows of one (b,hd); 4 waves x 32 q-rows. Key chunks of 64.
// r9 restructure (was LDS-pipe-bound at 12.6% MfmaUtil):
//  - 32x32x16 MFMA: halves LDS fragment traffic per q-row vs 16x16x32.
//  - swapped QK^T (mfma(K,Q)): lane holds P[32 keys][q=l31] in registers ->
//    P LDS round-trip eliminated; fixed-max softmax (max=0 as before) means
//    lsum is a single per-lane register, reduced once at the end.
//  - P -> PV A-frag via v_cvt_pk_bf16_f32 + half-wave exchange (shfl_xor 32).
//  - Q hoisted to registers (loaded once from global; L2-resident).
//  - K/V reg-staged double-buffer, loads issued at top of iter (latency hidden
//    under MFMA+softmax), one barrier per chunk.
__global__ __launch_bounds__(256) void attn_kernel(const ushort_t* __restrict__ qkv,
                                                   ushort_t* __restrict__ out) {
  __shared__ __align__(16) ushort_t Ks[2][64 * 72];   // [key][d], pad 72
  __shared__ __align__(16) ushort_t Vt[2][64 * 72];   // [d][key], pad 72
  int t = threadIdx.x;
  int lane = t & 63, wave = t >> 6;
  int l31 = lane & 31, h = lane >> 5, h8 = h * 8;
  int qt = blockIdx.x;
  int bh = blockIdx.y;
  int b = bh / NHEAD, hd = bh % NHEAD;
  size_t base = (size_t)b * SEQ * QKV_N + hd * 192;

  const float kscale = 0.125f * 1.44269504088896f;  // scale * log2(e)

  // Q fragments: B-operand rows (col=q=l31), element e <-> d = 16*ks + 8*h + e
  short8 qf[4];
  {
    const ushort_t* qp = qkv + base + (size_t)(qt * 128 + wave * 32 + l31) * QKV_N + h8;
    #pragma unroll
    for (int ks = 0; ks < 4; ++ks) qf[ks] = *(const short8*)(qp + ks * 16);
  }

  // staging: K -> 32B/thread linear; V -> transposed b16 writes (wave-uniform d-block)
  int srow = t >> 2, scol = (t & 3) * 16;
  int vrow = t & 63, vblk = wave * 16;
  short8 kr0, kr1, vr0, vr1;
  auto kv_load = [&](int kc) {
    const ushort_t* gk = qkv + base + (size_t)(kc * 64 + srow) * QKV_N + 64 + scol;
    kr0 = *(const short8*)gk;
    kr1 = *(const short8*)(gk + 8);
    const ushort_t* gv = qkv + base + (size_t)(kc * 64 + vrow) * QKV_N + 128 + vblk;
    vr0 = *(const short8*)gv;
    vr1 = *(const short8*)(gv + 8);
  };
  auto kv_write = [&](int buf) {
    *(short8*)&Ks[buf][srow * 72 + scol]     = kr0;
    *(short8*)&Ks[buf][srow * 72 + scol + 8] = kr1;
    #pragma unroll
    for (int e = 0; e < 8; ++e) {
      Vt[buf][(vblk + e) * 72 + vrow]     = (ushort_t)vr0[e];
      Vt[buf][(vblk + 8 + e) * 72 + vrow] = (ushort_t)vr1[e];
    }
  };

  f32x16 o0, o1;
  #pragma unroll
  for (int i = 0; i < 16; ++i) { o0[i] = 0.f; o1[i] = 0.f; }
  float lsum = 0.f;

  kv_load(0);
  kv_write(0);
  int cur = 0;
  for (int kc = 0; kc < SEQ / 64; ++kc) {
    __syncthreads();                       // buf[cur] staged & visible
    bool more = (kc + 1 < SEQ / 64);
    if (more) kv_load(kc + 1);             // global latency hides under compute

    // ---- QK^T (swapped): S^T[key, q], A = K rows, B = Q rows
    f32x16 s0, s1;
    #pragma unroll
    for (int i = 0; i < 16; ++i) { s0[i] = 0.f; s1[i] = 0.f; }
    __builtin_amdgcn_s_setprio(1);
    #pragma unroll
    for (int ks = 0; ks < 4; ++ks) {
      short8 k0 = *(const short8*)&Ks[cur][(l31)      * 72 + ks * 16 + h8];
      short8 k1 = *(const short8*)&Ks[cur][(32 + l31) * 72 + ks * 16 + h8];
      s0 = __builtin_amdgcn_mfma_f32_32x32x16_bf16(k0, qf[ks], s0, 0, 0, 0);
      s1 = __builtin_amdgcn_mfma_f32_32x32x16_bf16(k1, qf[ks], s1, 0, 0, 0);
    }
    __builtin_amdgcn_s_setprio(0);

    // ---- softmax numerator (fixed max = 0), packed to bf16 pairs in-register
    // lane's acc reg (4g+r) of tile t2 <-> key = 32*t2 + 8*g + 4*h + r, q = l31
    unsigned wpk[2][4][2];
    #pragma unroll
    for (int t2 = 0; t2 < 2; ++t2) {
      #pragma unroll
      for (int g = 0; g < 4; ++g) {
        float p0, p1, p2, p3;
        if (t2 == 0) {
          p0 = exp2f(s0[4 * g + 0] * kscale); p1 = exp2f(s0[4 * g + 1] * kscale);
          p2 = exp2f(s0[4 * g + 2] * kscale); p3 = exp2f(s0[4 * g + 3] * kscale);
        } else {
          p0 = exp2f(s1[4 * g + 0] * kscale); p1 = exp2f(s1[4 * g + 1] * kscale);
          p2 = exp2f(s1[4 * g + 2] * kscale); p3 = exp2f(s1[4 * g + 3] * kscale);
        }
        lsum += (p0 + p1) + (p2 + p3);
        wpk[t2][g][0] = cvtpk_bf16(p0, p1);
        wpk[t2][g][1] = cvtpk_bf16(p2, p3);
      }
    }

    // ---- PV: O[q, d] += P[q, keys] * V[keys, d]; A-frag assembled in-register.
    // For k-step k4 (keys 16*k4..+16): lane needs keys 16*k4 + 8*h + {0..7}
    //  = own wpk[t2][j2+h?] halves + partner half-wave's -> 1 shfl_xor(32) per word.
    #pragma unroll
    for (int k4 = 0; k4 < 4; ++k4) {
      int t2 = k4 >> 1, j2 = (k4 & 1) * 2;
      unsigned frag[4];
      #pragma unroll
      for (int c = 0; c < 2; ++c) {
        unsigned a  = wpk[t2][j2][c];       // keys 16*k4 + 4*h + {2c,2c+1}
        unsigned b2 = wpk[t2][j2 + 1][c];   // keys 16*k4 + 8 + 4*h + {2c,2c+1}
        unsigned snd = h ? a : b2;
        unsigned rcv = (unsigned)__shfl_xor((int)snd, 32, 64);
        frag[c]     = h ? rcv : a;
        frag[2 + c] = h ? b2 : rcv;
      }
      union { unsigned u[4]; short8 s8; } uc;
      uc.u[0] = frag[0]; uc.u[1] = frag[1]; uc.u[2] = frag[2]; uc.u[3] = frag[3];
      short8 ap = uc.s8;
      short8 v0 = *(const short8*)&Vt[cur][(l31)      * 72 + k4 * 16 + h8];
      short8 v1 = *(const short8*)&Vt[cur][(32 + l31) * 72 + k4 * 16 + h8];
      __builtin_amdgcn_s_setprio(1);
      o0 = __builtin_amdgcn_mfma_f32_32x32x16_bf16(ap, v0, o0, 0, 0, 0);
      o1 = __builtin_amdgcn_mfma_f32_32x32x16_bf16(ap, v1, o1, 0, 0, 0);
      __builtin_amdgcn_s_setprio(0);
    }

    if (more) kv_write(cur ^ 1);           // buf[cur^1]'s old readers done pre-barrier
    cur ^= 1;
  }

  // combine the two half-wave partial sums (each lane covered 32 of 64 keys/chunk)
  lsum += __shfl_xor(lsum, 32, 64);

  // epilogue: O reg (4g+r) of tile dt <-> row q = 8g + 4h + r, col d = 32*dt + l31
  size_t obase = (size_t)(b * SEQ + qt * 128 + wave * 32) * D_MODEL + hd * HDIM;
  #pragma unroll
  for (int g = 0; g < 4; ++g) {
    #pragma unroll
    for (int r = 0; r < 4; ++r) {
      int reg = 4 * g + r;
      int qrow = r + 8 * g + 4 * h;
      float inv = 1.0f / __shfl(lsum, qrow, 64);
      ushort_t* orow = out + obase + (size_t)qrow * D_MODEL;
      orow[l31]      = f2b(o0[reg] * inv);
      orow[32 + l31] = f2b(o1[reg] * inv);
    }
  }
}

// ---------------------------------------------------------------- launch
extern "C" void kernel_launch(void* const* d_in, const int* in_sizes, int n_in,
                              void* d_out, int out_size, void* d_ws, size_t ws_size,
                              hipStream_t stream) {
  const float* x_in  = (const float*)d_in[0];
  const float* qkv_w = (const float*)d_in[1];
  const float* qkv_b = (const float*)d_in[2];
  const float* out_w = (const float*)d_in[3];
  const float* out_b = (const float*)d_in[4];
  const float* ln1_w = (const float*)d_in[5];
  const float* ln1_b = (const float*)d_in[6];
  const float* fc1_w = (const float*)d_in[7];
  const float* fc1_b = (const float*)d_in[8];
  const float* fc2_w = (const float*)d_in[9];
  const float* fc2_b = (const float*)d_in[10];
  const float* ln2_w = (const float*)d_in[11];
  const float* ln2_b = (const float*)d_in[12];

  char* ws = (char*)d_ws;
  size_t off = 0;
  auto alloc = [&](size_t bytes) -> void* {
    void* p = ws + off; off += (bytes + 255) & ~(size_t)255; return p;
  };
  float*    buf_x  = (float*)   alloc((size_t)NTOK * D_MODEL * 4);
  float*    buf_x2 = (float*)   alloc((size_t)NTOK * D_MODEL * 4);
  ushort_t* bigb   = (ushort_t*)alloc((size_t)NTOK * D_FF * 2);     // qkv_a / mlp_b union
  ushort_t* h_b    = (ushort_t*)alloc((size_t)NTOK * D_MODEL * 2);
  ushort_t* at_b   = (ushort_t*)alloc((size_t)NTOK * D_MODEL * 2);
  ushort_t* qkvT   = (ushort_t*)alloc((size_t)QKV_N * D_MODEL * 2);
  ushort_t* outT   = (ushort_t*)alloc((size_t)D_MODEL * D_MODEL * 2);
  ushort_t* f1T    = (ushort_t*)alloc((size_t)D_FF * D_MODEL * 2);
  ushort_t* f2T    = (ushort_t*)alloc((size_t)D_MODEL * D_FF * 2);

  ushort_t* qkv_a = bigb;
  ushort_t* mlp_b = bigb;

  for (int l = 0; l < 4; ++l) {
    const float* resid_in = (l == 0) ? x_in : buf_x;
    transpose_layer<<<6912, dim3(32, 8), 0, stream>>>(
        qkv_w + (size_t)l * D_MODEL * QKV_N, out_w + (size_t)l * D_MODEL * D_MODEL,
        fc1_w + (size_t)l * D_MODEL * D_FF,  fc2_w + (size_t)l * D_FF * D_MODEL,
        qkvT, outT, f1T, f2T);
    ln_kernel<<<NTOK, 256, 0, stream>>>(resid_in, ln1_w + l * D_MODEL, ln1_b + l * D_MODEL, h_b);
    gemm_kernel<0, 128><<<dim3(QKV_N / 128, NTOK / 128), 256, 0, stream>>>(
        h_b, qkvT, qkv_b + l * QKV_N, nullptr, nullptr, qkv_a, NTOK, QKV_N, D_MODEL);
    attn_kernel<<<dim3(SEQ / 128, 2 * NHEAD), 256, 0, stream>>>(qkv_a, at_b);
    gemm_kernel<2, 64><<<dim3(D_MODEL / 64, NTOK / 128), 256, 0, stream>>>(
        at_b, outT, out_b + l * D_MODEL, resid_in, buf_x2, nullptr, NTOK, D_MODEL, D_MODEL);
    ln_kernel<<<NTOK, 256, 0, stream>>>(buf_x2, ln2_w + l * D_MODEL, ln2_b + l * D_MODEL, h_b);
    gemm_kernel<1, 128><<<dim3(D_FF / 128, NTOK / 128), 256, 0, stream>>>(
        h_b, f1T, fc1_b + l * D_FF, nullptr, nullptr, mlp_b, NTOK, D_FF, D_MODEL);
    float* x_next = (l < 3) ? buf_x : (float*)d_out;
    gemm_kernel<2, 64><<<dim3(D_MODEL / 64, NTOK / 128), 256, 0, stream>>>(
        mlp_b, f2T, fc2_b + l * D_MODEL, buf_x2, x_next, nullptr, NTOK, D_MODEL, D_FF);
  }
  (void)in_sizes; (void)n_in; (void)out_size; (void)ws_size;
}

// Round 2
// 987.590 us; speedup vs baseline: 1.0805x; 1.0614x over previous
//
#include <hip/hip_runtime.h>
#include <stdint.h>
#include <math.h>

// Problem constants
#define D_MODEL 768
#define NTOK    4096      // B*S = 2*2048
#define SEQ     2048
#define NHEAD   12
#define HDIM    64
#define D_FF    3072
#define QKV_N   2304      // 3*D_MODEL

typedef unsigned short ushort_t;  // raw bf16 bits
typedef short  sh4    __attribute__((ext_vector_type(4)));   // NOT short4: HIP defines that
typedef short  short8 __attribute__((ext_vector_type(8)));
typedef float  f32x4  __attribute__((ext_vector_type(4)));
typedef float  f32x16 __attribute__((ext_vector_type(16)));

__device__ __forceinline__ float b2f(ushort_t u) {
  union { unsigned int u; float f; } v; v.u = ((unsigned int)u) << 16; return v.f;
}
__device__ __forceinline__ ushort_t f2b(float f) {
  union { float f; unsigned int u; } v; v.f = f;
  unsigned int u = v.u;
  return (ushort_t)((u + 0x7fffu + ((u >> 16) & 1u)) >> 16);  // RNE
}
__device__ __forceinline__ unsigned cvtpk_bf16(float lo, float hi) {
  unsigned r;
  asm("v_cvt_pk_bf16_f32 %0, %1, %2" : "=v"(r) : "v"(lo), "v"(hi));
  return r;
}

// ---------------------------------------------------------------- layer transpose+cast
// All 4 weight matrices of one layer, [K,N] fp32 -> [N,K] bf16, one launch.
__global__ __launch_bounds__(256) void transpose_layer(
    const float* __restrict__ qkv_w, const float* __restrict__ out_w,
    const float* __restrict__ fc1_w, const float* __restrict__ fc2_w,
    ushort_t* __restrict__ qkvT, ushort_t* __restrict__ outT,
    ushort_t* __restrict__ f1T, ushort_t* __restrict__ f2T) {
  __shared__ ushort_t tile[32][33];
  int bid = blockIdx.x;
  const float* src; ushort_t* dst; int K, N, tn, tk;
  if (bid < 1728)      { src = qkv_w; dst = qkvT; K = 768;  N = 2304; tn = bid % 72;  tk = bid / 72; }
  else if (bid < 2304) { int b = bid - 1728; src = out_w; dst = outT; K = 768;  N = 768;  tn = b % 24; tk = b / 24; }
  else if (bid < 4608) { int b = bid - 2304; src = fc1_w; dst = f1T;  K = 768;  N = 3072; tn = b % 96; tk = b / 96; }
  else                 { int b = bid - 4608; src = fc2_w; dst = f2T;  K = 3072; N = 768;  tn = b % 24; tk = b / 24; }
  int n0 = tn * 32, k0 = tk * 32;
  int tx = threadIdx.x, ty = threadIdx.y;       // (32,8)
  #pragma unroll
  for (int i = 0; i < 32; i += 8)
    tile[ty + i][tx] = f2b(src[(size_t)(k0 + ty + i) * N + n0 + tx]);
  __syncthreads();
  #pragma unroll
  for (int i = 0; i < 32; i += 8)
    dst[(size_t)(n0 + ty + i) * K + k0 + tx] = tile[tx][ty + i];
}

// ---------------------------------------------------------------- layernorm
__global__ __launch_bounds__(256) void ln_kernel(const float* __restrict__ x,
                                                 const float* __restrict__ w,
                                                 const float* __restrict__ b,
                                                 ushort_t* __restrict__ out) {
  __shared__ float red[4];
  int tok = blockIdx.x, t = threadIdx.x;
  const float* xr = x + (size_t)tok * D_MODEL;
  float v0 = xr[t], v1 = xr[t + 256], v2 = xr[t + 512];
  float s = v0 + v1 + v2;
  #pragma unroll
  for (int o = 1; o < 64; o <<= 1) s += __shfl_xor(s, o, 64);
  if ((t & 63) == 0) red[t >> 6] = s;
  __syncthreads();
  float mean = (red[0] + red[1] + red[2] + red[3]) * (1.0f / 768.0f);
  __syncthreads();
  float d0 = v0 - mean, d1 = v1 - mean, d2 = v2 - mean;
  float q = d0 * d0 + d1 * d1 + d2 * d2;
  #pragma unroll
  for (int o = 1; o < 64; o <<= 1) q += __shfl_xor(q, o, 64);
  if ((t & 63) == 0) red[t >> 6] = q;
  __syncthreads();
  float var = (red[0] + red[1] + red[2] + red[3]) * (1.0f / 768.0f);
  float rs = rsqrtf(var + 1e-5f);
  ushort_t* orow = out + (size_t)tok * D_MODEL;
  orow[t]       = f2b(d0 * rs * w[t]       + b[t]);
  orow[t + 256] = f2b(d1 * rs * w[t + 256] + b[t + 256]);
  orow[t + 512] = f2b(d2 * rs * w[t + 512] + b[t + 512]);
}

// ---------------------------------------------------------------- GEMM (MFMA bf16)
// C[M,N] = A[M,K] * BT[N,K]^T + bias, 128 x TN tile, BK=32, 256 threads.
// DOUBLE-BUFFERED K-loop: one barrier/iter; prefetch of tile k+1 issued right
// after the barrier -> it gets the whole MFMA phase to fly before the next
// barrier's vmcnt drain (vs ~0 cycles in the 2-barrier structure).
// EPI: 0 bias->bf16 | 1 bias+gelu->bf16 | 2 bias+resid->fp32
template <int EPI, int TN>
__global__ __launch_bounds__(256) void gemm_kernel(
    const ushort_t* __restrict__ A, const ushort_t* __restrict__ BT,
    const float* __restrict__ bias, const float* __restrict__ resid,
    float* __restrict__ Cf, ushort_t* __restrict__ Cb, int M, int N, int K) {
  constexpr int NI = (TN == 128) ? 4 : 2;
  __shared__ ushort_t As[2][128 * 32];
  __shared__ ushort_t Bs[2][TN * 32];
  int t = threadIdx.x;
  int lane = t & 63, wave = t >> 6;
  int m0 = blockIdx.y * 128, n0 = blockIdx.x * TN;
  int wm = (TN == 128) ? (wave & 1) * 64 : wave * 32;
  int wn = (TN == 128) ? (wave >> 1) * 64 : 0;
  int quad = lane >> 4, l16 = lane & 15;
  int kq = quad * 8;
  int lrow = lane >> 2, lcol = (lane & 3) * 8;   // staging: 16B per lane

  auto stage = [&](int k0, int buf) {
    #pragma unroll
    for (int c = 0; c < 2; ++c) {
      int rowA = wave * 32 + c * 16 + lrow;
      const ushort_t* ga = A + (size_t)(m0 + rowA) * K + k0 + lcol;
      ushort_t* la = &As[buf][(wave * 32 + c * 16) * 32];
      __builtin_amdgcn_global_load_lds((const __attribute__((address_space(1))) void*)ga,
                                       (__attribute__((address_space(3))) void*)la, 16, 0, 0);
      if (TN == 128 || c == 0) {
        int rowB = (TN == 128) ? rowA : (wave * 16 + lrow);
        const ushort_t* gb = BT + (size_t)(n0 + rowB) * K + k0 + lcol;
        ushort_t* lb = (TN == 128) ? &Bs[buf][(wave * 32 + c * 16) * 32]
                                   : &Bs[buf][(wave * 16) * 32];
        __builtin_amdgcn_global_load_lds((const __attribute__((address_space(1))) void*)gb,
                                         (__attribute__((address_space(3))) void*)lb, 16, 0, 0);
      }
    }
  };

  f32x4 acc[NI][4];
  #pragma unroll
  for (int i = 0; i < NI; ++i)
    #pragma unroll
    for (int j = 0; j < 4; ++j) acc[i][j] = (f32x4){0.f, 0.f, 0.f, 0.f};

  stage(0, 0);                      // prologue prefetch
  int nk = K / 32;
  for (int ki = 0; ki < nk; ++ki) {
    int cur = ki & 1;
    __syncthreads();                // tile ki resident; prev reads of buf[cur^1] done
    if (ki + 1 < nk) stage((ki + 1) * 32, cur ^ 1);
    short8 af[NI], bf[4];
    #pragma unroll
    for (int i = 0; i < NI; ++i)
      af[i] = *(const short8*)&As[cur][(wm + i * 16 + l16) * 32 + kq];
    #pragma unroll
    for (int j = 0; j < 4; ++j)
      bf[j] = *(const short8*)&Bs[cur][(wn + j * 16 + l16) * 32 + kq];
    #pragma unroll
    for (int i = 0; i < NI; ++i)
      #pragma unroll
      for (int j = 0; j < 4; ++j)
        acc[i][j] = __builtin_amdgcn_mfma_f32_16x16x32_bf16(af[i], bf[j], acc[i][j], 0, 0, 0);
  }

  #pragma unroll
  for (int i = 0; i < NI; ++i) {
    #pragma unroll
    for (int j = 0; j < 4; ++j) {
      int col = n0 + wn + j * 16 + l16;
      float bv = bias[col];
      #pragma unroll
      for (int r = 0; r < 4; ++r) {
        int row = m0 + wm + i * 16 + quad * 4 + r;
        float v = acc[i][j][r] + bv;
        if (EPI == 1) v = 0.5f * v * (1.0f + erff(v * 0.70710678118654752f));
        if (EPI == 2) v += resid[(size_t)row * N + col];
        if (EPI == 2) Cf[(size_t)row * N + col] = v;
        else          Cb[(size_t)row * N + col] = f2b(v);
      }
    }
  }
}

// ---------------------------------------------------------------- attention (MFMA 32x32, split-K in block)
// qkv bf16 [NTOK, 2304]; token t, head hd: [hd*192 + (q:0|k:64|v:128) + d]
// r10: occupancy fix. r9 was 384 blocks (1.5/CU, 1 wave/SIMD) -> pure latency
// serialization (~3900 cyc/chunk vs ~530 issue cyc). Now: q-tile 64, grid
// 32x24 = 768 blocks = exactly 3/CU; 4 waves; wave-pair 0 (waves 0,1) handles
// EVEN 64-key chunks, pair 1 ODD chunks, same 64 q-rows. Fixed-max softmax
// makes (O, lsum) partials additive -> combined once at the end via LDS.
//  - swapped QK^T (mfma(K,Q)): P lane-local, no LDS round-trip (r9).
//  - K/V reg-staged, 2 chunks per superstep; next loads issued under compute.
//  - V-transpose staged with paired b32 writes (2 keys/dword, half the ops).
//  - __launch_bounds__(256,3): 3 waves/SIMD required for 3 blocks/CU.
__global__ __launch_bounds__(256, 3) void attn_kernel(const ushort_t* __restrict__ qkv,
                                                      ushort_t* __restrict__ out) {
  __shared__ __align__(16) ushort_t Ks[2][64 * 72];   // [key][d], pad 72; buf = chunk parity
  __shared__ __align__(16) ushort_t Vt[2][64 * 72];   // [d][key], pad 72
  int t = threadIdx.x;
  int lane = t & 63, wave = t >> 6;
  int l31 = lane & 31, h = lane >> 5, h8 = h * 8;
  int pair = wave >> 1;          // 0: even chunks, 1: odd chunks
  int wq = wave & 1;             // q-row block within tile
  int qt = blockIdx.x;
  int bh = blockIdx.y;
  int b = bh / NHEAD, hd = bh % NHEAD;
  size_t base = (size_t)b * SEQ * QKV_N + hd * 192;

  const float kscale = 0.125f * 1.44269504088896f;  // scale * log2(e)

  // Q fragments: B-operand rows (col=q=l31), element e <-> d = 16*ks + 8*h + e
  short8 qf[4];
  {
    const ushort_t* qp = qkv + base + (size_t)(qt * 64 + wq * 32 + l31) * QKV_N + h8;
    #pragma unroll
    for (int ks = 0; ks < 4; ++ks) qf[ks] = *(const short8*)(qp + ks * 16);
  }

  // staging (all 256 threads stage BOTH chunks of a superstep):
  // K: thread -> row srow, 16 d-elems at scol (2x b128 LDS writes)
  // V: thread -> keys (vk, vk+1) x 8 d at vd; packed b32 transposed writes
  int srow = t >> 2, scol = (t & 3) * 16;
  int vk = (t & 31) * 2, vd = (t >> 5) * 8;
  short8 krA[2], krB[2], vrA[2], vrB[2];
  auto kv_load = [&](int c, int p) {
    const ushort_t* gk = qkv + base + (size_t)(c * 64 + srow) * QKV_N + 64 + scol;
    krA[p] = *(const short8*)gk;
    krB[p] = *(const short8*)(gk + 8);
    const ushort_t* gv = qkv + base + (size_t)(c * 64 + vk) * QKV_N + 128 + vd;
    vrA[p] = *(const short8*)gv;
    vrB[p] = *(const short8*)(gv + QKV_N);
  };
  auto kv_write = [&](int p) {
    *(short8*)&Ks[p][srow * 72 + scol]     = krA[p];
    *(short8*)&Ks[p][srow * 72 + scol + 8] = krB[p];
    unsigned* vtw = (unsigned*)&Vt[p][0];
    #pragma unroll
    for (int e = 0; e < 8; ++e) {
      unsigned pk = (unsigned)(unsigned short)vrA[p][e] |
                    ((unsigned)(unsigned short)vrB[p][e] << 16);
      vtw[(vd + e) * 36 + (vk >> 1)] = pk;   // Vt[d=vd+e][keys vk,vk+1]
    }
  };

  f32x16 o0, o1;
  #pragma unroll
  for (int i = 0; i < 16; ++i) { o0[i] = 0.f; o1[i] = 0.f; }
  float lsum = 0.f;

  kv_load(0, 0);
  kv_load(1, 1);
  for (int it = 0; it < SEQ / 128; ++it) {
    kv_write(0);
    kv_write(1);
    __syncthreads();                       // both chunks staged; prev reads done
    if (it + 1 < SEQ / 128) {              // next superstep's loads fly under compute
      kv_load(2 * it + 2, 0);
      kv_load(2 * it + 3, 1);
    }

    // ---- QK^T (swapped): S^T[key, q], A = K rows, B = Q rows; buf = pair
    f32x16 s0, s1;
    #pragma unroll
    for (int i = 0; i < 16; ++i) { s0[i] = 0.f; s1[i] = 0.f; }
    __builtin_amdgcn_s_setprio(1);
    #pragma unroll
    for (int ks = 0; ks < 4; ++ks) {
      short8 k0 = *(const short8*)&Ks[pair][(l31)      * 72 + ks * 16 + h8];
      short8 k1 = *(const short8*)&Ks[pair][(32 + l31) * 72 + ks * 16 + h8];
      s0 = __builtin_amdgcn_mfma_f32_32x32x16_bf16(k0, qf[ks], s0, 0, 0, 0);
      s1 = __builtin_amdgcn_mfma_f32_32x32x16_bf16(k1, qf[ks], s1, 0, 0, 0);
    }
    __builtin_amdgcn_s_setprio(0);

    // ---- softmax numerator (fixed max = 0), packed to bf16 pairs in-register
    // lane's acc reg (4g+r) of tile t2 <-> key = 32*t2 + 8*g + 4*h + r, q = l31
    unsigned wpk[2][4][2];
    #pragma unroll
    for (int t2 = 0; t2 < 2; ++t2) {
      #pragma unroll
      for (int g = 0; g < 4; ++g) {
        float p0, p1, p2, p3;
        if (t2 == 0) {
          p0 = exp2f(s0[4 * g + 0] * kscale); p1 = exp2f(s0[4 * g + 1] * kscale);
          p2 = exp2f(s0[4 * g + 2] * kscale); p3 = exp2f(s0[4 * g + 3] * kscale);
        } else {
          p0 = exp2f(s1[4 * g + 0] * kscale); p1 = exp2f(s1[4 * g + 1] * kscale);
          p2 = exp2f(s1[4 * g + 2] * kscale); p3 = exp2f(s1[4 * g + 3] * kscale);
        }
        lsum += (p0 + p1) + (p2 + p3);
        wpk[t2][g][0] = cvtpk_bf16(p0, p1);
        wpk[t2][g][1] = cvtpk_bf16(p2, p3);
      }
    }

    // ---- PV: O[q, d] += P[q, keys] * V[keys, d]; A-frag assembled in-register.
    #pragma unroll
    for (int k4 = 0; k4 < 4; ++k4) {
      int t2 = k4 >> 1, j2 = (k4 & 1) * 2;
      unsigned frag[4];
      #pragma unroll
      for (int c = 0; c < 2; ++c) {
        unsigned a  = wpk[t2][j2][c];       // keys 16*k4 + 4*h + {2c,2c+1}
        unsigned b2 = wpk[t2][j2 + 1][c];   // keys 16*k4 + 8 + 4*h + {2c,2c+1}
        unsigned snd = h ? a : b2;
        unsigned rcv = (unsigned)__shfl_xor((int)snd, 32, 64);
        frag[c]     = h ? rcv : a;
        frag[2 + c] = h ? b2 : rcv;
      }
      union { unsigned u[4]; short8 s8; } uc;
      uc.u[0] = frag[0]; uc.u[1] = frag[1]; uc.u[2] = frag[2]; uc.u[3] = frag[3];
      short8 ap = uc.s8;
      short8 v0 = *(const short8*)&Vt[pair][(l31)      * 72 + k4 * 16 + h8];
      short8 v1 = *(const short8*)&Vt[pair][(32 + l31) * 72 + k4 * 16 + h8];
      __builtin_amdgcn_s_setprio(1);
      o0 = __builtin_amdgcn_mfma_f32_32x32x16_bf16(ap, v0, o0, 0, 0, 0);
      o1 = __builtin_amdgcn_mfma_f32_32x32x16_bf16(ap, v1, o1, 0, 0, 0);
      __builtin_amdgcn_s_setprio(0);
    }
    __syncthreads();                       // all reads done before next superstep writes
  }

  // ---- cross-pair combine via LDS overlay on Ks (64+64 lanes x 33 floats)
  float* cb = (float*)&Ks[0][0];
  if (wave >= 2) {
    int slot = ((wave - 2) * 64 + lane) * 33;
    #pragma unroll
    for (int i = 0; i < 16; ++i) { cb[slot + i] = o0[i]; cb[slot + 16 + i] = o1[i]; }
    cb[slot + 32] = lsum;
  }
  __syncthreads();
  if (wave < 2) {
    int slot = (wave * 64 + lane) * 33;
    #pragma unroll
    for (int i = 0; i < 16; ++i) { o0[i] += cb[slot + i]; o1[i] += cb[slot + 16 + i]; }
    lsum += cb[slot + 32];
    // each lane covered half the keys of its chunks -> combine half-waves
    lsum += __shfl_xor(lsum, 32, 64);

    // epilogue: O reg (4g+r) <-> row q = 8g + 4h + r, col d = l31 / 32+l31
    size_t obase = (size_t)(b * SEQ + qt * 64 + wave * 32) * D_MODEL + hd * HDIM;
    #pragma unroll
    for (int g = 0; g < 4; ++g) {
      #pragma unroll
      for (int r = 0; r < 4; ++r) {
        int reg = 4 * g + r;
        int qrow = r + 8 * g + 4 * h;
        float inv = 1.0f / __shfl(lsum, qrow, 64);
        ushort_t* orow = out + obase + (size_t)qrow * D_MODEL;
        orow[l31]      = f2b(o0[reg] * inv);
        orow[32 + l31] = f2b(o1[reg] * inv);
      }
    }
  }
}

// ---------------------------------------------------------------- launch
extern "C" void kernel_launch(void* const* d_in, const int* in_sizes, int n_in,
                              void* d_out, int out_size, void* d_ws, size_t ws_size,
                              hipStream_t stream) {
  const float* x_in  = (const float*)d_in[0];
  const float* qkv_w = (const float*)d_in[1];
  const float* qkv_b = (const float*)d_in[2];
  const float* out_w = (const float*)d_in[3];
  const float* out_b = (const float*)d_in[4];
  const float* ln1_w = (const float*)d_in[5];
  const float* ln1_b = (const float*)d_in[6];
  const float* fc1_w = (const float*)d_in[7];
  const float* fc1_b = (const float*)d_in[8];
  const float* fc2_w = (const float*)d_in[9];
  const float* fc2_b = (const float*)d_in[10];
  const float* ln2_w = (const float*)d_in[11];
  const float* ln2_b = (const float*)d_in[12];

  char* ws = (char*)d_ws;
  size_t off = 0;
  auto alloc = [&](size_t bytes) -> void* {
    void* p = ws + off; off += (bytes + 255) & ~(size_t)255; return p;
  };
  float*    buf_x  = (float*)   alloc((size_t)NTOK * D_MODEL * 4);
  float*    buf_x2 = (float*)   alloc((size_t)NTOK * D_MODEL * 4);
  ushort_t* bigb   = (ushort_t*)alloc((size_t)NTOK * D_FF * 2);     // qkv_a / mlp_b union
  ushort_t* h_b    = (ushort_t*)alloc((size_t)NTOK * D_MODEL * 2);
  ushort_t* at_b   = (ushort_t*)alloc((size_t)NTOK * D_MODEL * 2);
  ushort_t* qkvT   = (ushort_t*)alloc((size_t)QKV_N * D_MODEL * 2);
  ushort_t* outT   = (ushort_t*)alloc((size_t)D_MODEL * D_MODEL * 2);
  ushort_t* f1T    = (ushort_t*)alloc((size_t)D_FF * D_MODEL * 2);
  ushort_t* f2T    = (ushort_t*)alloc((size_t)D_MODEL * D_FF * 2);

  ushort_t* qkv_a = bigb;
  ushort_t* mlp_b = bigb;

  for (int l = 0; l < 4; ++l) {
    const float* resid_in = (l == 0) ? x_in : buf_x;
    transpose_layer<<<6912, dim3(32, 8), 0, stream>>>(
        qkv_w + (size_t)l * D_MODEL * QKV_N, out_w + (size_t)l * D_MODEL * D_MODEL,
        fc1_w + (size_t)l * D_MODEL * D_FF,  fc2_w + (size_t)l * D_FF * D_MODEL,
        qkvT, outT, f1T, f2T);
    ln_kernel<<<NTOK, 256, 0, stream>>>(resid_in, ln1_w + l * D_MODEL, ln1_b + l * D_MODEL, h_b);
    gemm_kernel<0, 128><<<dim3(QKV_N / 128, NTOK / 128), 256, 0, stream>>>(
        h_b, qkvT, qkv_b + l * QKV_N, nullptr, nullptr, qkv_a, NTOK, QKV_N, D_MODEL);
    attn_kernel<<<dim3(SEQ / 64, 2 * NHEAD), 256, 0, stream>>>(qkv_a, at_b);
    gemm_kernel<2, 64><<<dim3(D_MODEL / 64, NTOK / 128), 256, 0, stream>>>(
        at_b, outT, out_b + l * D_MODEL, resid_in, buf_x2, nullptr, NTOK, D_MODEL, D_MODEL);
    ln_kernel<<<NTOK, 256, 0, stream>>>(buf_x2, ln2_w + l * D_MODEL, ln2_b + l * D_MODEL, h_b);
    gemm_kernel<1, 128><<<dim3(D_FF / 128, NTOK / 128), 256, 0, stream>>>(
        h_b, f1T, fc1_b + l * D_FF, nullptr, nullptr, mlp_b, NTOK, D_FF, D_MODEL);
    float* x_next = (l < 3) ? buf_x : (float*)d_out;
    gemm_kernel<2, 64><<<dim3(D_MODEL / 64, NTOK / 128), 256, 0, stream>>>(
        mlp_b, f2T, fc2_b + l * D_MODEL, buf_x2, x_next, nullptr, NTOK, D_MODEL, D_FF);
  }
  (void)in_sizes; (void)n_in; (void)out_size; (void)ws_size;
}